// Round 3
// baseline (131.774 us; speedup 1.0000x reference)
//
#include <hip/hip_runtime.h>
#include <hip/hip_bf16.h>
#include <stdint.h>

#define HID 160
#define HID4 640
#define FDIM 32
#define NPIX 1024

// Gaussian blur taps: e = exp(-0.5); k = [e,1,e]/(1+2e)
#define GK0 0.27406862f
#define GK1 0.45186276f

typedef __attribute__((ext_vector_type(8))) short short8;
typedef __attribute__((ext_vector_type(4))) float f32x4;

__device__ __forceinline__ ushort f2b(float f) {
  union { float f; uint32_t u; } v; v.f = f;
  uint32_t u = v.u;
  u += 0x7fffu + ((u >> 16) & 1u);   // RNE
  return (ushort)(u >> 16);
}
__device__ __forceinline__ float b2f(ushort s) {
  union { uint32_t u; float f; } v; v.u = ((uint32_t)s) << 16;
  return v.f;
}

// async global->LDS, 16B per lane; LDS dest = wave-uniform base + lane*16
__device__ __forceinline__ void gload16(const ushort* g, ushort* l) {
  __builtin_amdgcn_global_load_lds(
      (const __attribute__((address_space(1))) void*)g,
      (__attribute__((address_space(3))) void*)l, 16, 0, 0);
}

// ------------------------------------------------------------------
// attn per-sample scratch (shared by both kernels via unions)
// ------------------------------------------------------------------
struct AttnSM {
  float am[FDIM][FDIM + 1];
  float tmp[FDIM][FDIM + 1];
  float bl[FDIM][FDIM + 1];
  float rowsum[FDIM], colsum[FDIM];
  float redv[4];
  int redi[4];
};

union GemmSM {
  struct {
    ushort la[2][4096];   // A tile dbuf: 128x32 each, linear
    ushort lb[2][2048];   // B tile dbuf: 64x32 each, linear
  } g;
  AttnSM a;
};

union PrepSM {
  float t[32][33];
  AttnSM a;
};

__device__ void attn_block(AttnSM& sm, const float* __restrict__ attn,
                           float* __restrict__ pp, int n) {
  const int tid = threadIdx.x;
  const float* base = attn + (size_t)n * (16 * NPIX);
  float4 a = make_float4(0.f, 0.f, 0.f, 0.f);
#pragma unroll
  for (int q = 0; q < 16; ++q) {
    float4 v = *(const float4*)(base + q * NPIX + tid * 4);
    a.x += v.x; a.y += v.y; a.z += v.z; a.w += v.w;
  }
  {
    const int f0 = tid * 4;
    const int r = f0 >> 5, c = f0 & 31;
    sm.am[r][c + 0] = a.x * 0.0625f;
    sm.am[r][c + 1] = a.y * 0.0625f;
    sm.am[r][c + 2] = a.z * 0.0625f;
    sm.am[r][c + 3] = a.w * 0.0625f;
  }
  __syncthreads();
  for (int f = tid; f < NPIX; f += 256) {
    int r = f >> 5, c = f & 31;
    int rm = (r == 0) ? 1 : r - 1;
    int rp = (r == 31) ? 30 : r + 1;
    sm.tmp[r][c] = GK0 * sm.am[rm][c] + GK1 * sm.am[r][c] + GK0 * sm.am[rp][c];
  }
  __syncthreads();
  for (int f = tid; f < NPIX; f += 256) {
    int r = f >> 5, c = f & 31;
    int cm = (c == 0) ? 1 : c - 1;
    int cp = (c == 31) ? 30 : c + 1;
    sm.bl[r][c] = GK0 * sm.tmp[r][cm] + GK1 * sm.tmp[r][c] + GK0 * sm.tmp[r][cp];
  }
  __syncthreads();
  // argmax of blurred map (normalization is affine+positive => argmax-invariant)
  float bv = -1e30f; int bi = 0;
  for (int f = tid; f < NPIX; f += 256) {
    float v = sm.bl[f >> 5][f & 31];
    if (v > bv || (v == bv && f < bi)) { bv = v; bi = f; }
  }
  for (int off = 32; off > 0; off >>= 1) {
    float ov = __shfl_down(bv, off);
    int oi = __shfl_down(bi, off);
    if (ov > bv || (ov == bv && oi < bi)) { bv = ov; bi = oi; }
  }
  if ((tid & 63) == 0) { sm.redv[tid >> 6] = bv; sm.redi[tid >> 6] = bi; }
  for (int f = tid; f < NPIX; f += 256) {
    int r = f >> 5, c = f & 31;
    float s = 1.f / (1.f + expf(-sm.am[r][c]));
    sm.tmp[r][c] = fminf(fmaxf(s, 1e-4f), 0.9999f);
  }
  __syncthreads();
  if (tid < 32) {
    float s = 0.f;
    for (int c = 0; c < 32; ++c) s += sm.tmp[tid][c];
    sm.rowsum[tid] = s;
  } else if (tid < 64) {
    int c = tid - 32;
    float s = 0.f;
    for (int r = 0; r < 32; ++r) s += sm.tmp[r][c];
    sm.colsum[c] = s;
  }
  __syncthreads();
  if (tid == 0) {
    float bestv = sm.redv[0]; int besti = sm.redi[0];
    for (int w = 1; w < 4; ++w)
      if (sm.redv[w] > bestv || (sm.redv[w] == bestv && sm.redi[w] < besti)) {
        bestv = sm.redv[w]; besti = sm.redi[w];
      }
    int px = besti & 31, py = besti >> 5;
    int c0 = max(0, px - 3), c1 = min(32, px + 3);
    float sx = 0.f;
    for (int c = c0; c < c1; ++c) sx += sm.colsum[c];
    float psx = (sx / (32.f * (float)(c1 - c0))) * 32.f;
    int r0 = max(0, py - 3), r1 = min(32, py + 3);
    float sy = 0.f;
    for (int r = r0; r < r1; ++r) sy += sm.rowsum[r];
    float psy = (sy / (32.f * (float)(r1 - r0))) * 32.f;
    pp[n * 4 + 0] = (float)px;
    pp[n * 4 + 1] = (float)py;
    pp[n * 4 + 2] = psx;
    pp[n * 4 + 3] = psy;
  }
}

// ------------------------------------------------------------------
// Fused: 128x64-tile MFMA GEMM, LDS double-buffer with counted vmcnt
// (loads for tile t+1 in flight across tile t's MFMA), XOR-swizzled
// LDS via pre-swizzled global source; + attn blocks in the same grid.
// ------------------------------------------------------------------
template <int K>
__global__ __launch_bounds__(256) void gemm_attn(
    const ushort* __restrict__ A0, const ushort* __restrict__ A1,
    const ushort* __restrict__ W0, const ushort* __restrict__ W1,
    const float* __restrict__ B0, const float* __restrict__ B1,
    ushort* __restrict__ O0, ushort* __restrict__ O1,
    const float* __restrict__ attn, float* __restrict__ pp,
    int attn_base, int n_gemm) {
  __shared__ GemmSM sm;
  const int tid = threadIdx.x;

  if ((int)blockIdx.x >= n_gemm) {
    attn_block(sm.a, attn, pp, attn_base + (int)blockIdx.x - n_gemm);
    return;
  }

  const int bid = blockIdx.x;
  const int half = n_gemm >> 1;
  const int chain = bid >= half;
  const int r = chain ? bid - half : bid;
  const int bn = (r % 10) * 64;
  const int bm = (r / 10) * 128;
  const ushort* A = chain ? A1 : A0;
  const ushort* W = chain ? W1 : W0;
  const float* bias = chain ? B1 : B0;
  ushort* O = chain ? O1 : O0;

  const int lane = tid & 63;
  const int wid = tid >> 6;
  const int wr = (wid >> 1) * 64;   // wave's row block in 128
  const int wc = (wid & 1) * 32;    // wave's col block in 64
  const int l15 = lane & 15;
  const int kq = (lane >> 4) * 8;

  const int rstage = tid >> 2;       // 0..63 source row (within 64-row half)
  const int cstage = (tid & 3) * 8;  // k-seg
  // pre-swizzled source k-offset: read side XORs the same pattern
  const int cs_sw = cstage ^ ((rstage & 6) << 2);

  ushort* la = &sm.g.la[0][0];
  ushort* lb = &sm.g.lb[0][0];
  const int ldsw = wid * 512;        // wave-uniform elem offset (lane adds *8)

  const size_t arow0 = (size_t)(bm + rstage) * K + cs_sw;
  const size_t arow1 = (size_t)(bm + 64 + rstage) * K + cs_sw;
  const size_t brow  = (size_t)(bn + rstage) * K + cs_sw;

  // prologue: stage tile 0 into buf 0
  gload16(A + arow0, la + ldsw);
  gload16(A + arow1, la + 2048 + ldsw);
  gload16(W + brow,  lb + ldsw);

  constexpr int NT = K / 32;
  f32x4 acc[4][2] = {};
  for (int t = 0; t < NT; ++t) {
    const int cur = t & 1;
    if (t + 1 < NT) {
      const int k1 = (t + 1) * 32;
      const int nxt = cur ^ 1;
      gload16(A + arow0 + k1, la + nxt * 4096 + ldsw);
      gload16(A + arow1 + k1, la + nxt * 4096 + 2048 + ldsw);
      gload16(W + brow + k1,  lb + nxt * 2048 + ldsw);
      asm volatile("s_waitcnt vmcnt(3)" ::: "memory");  // tile t done, t+1 in flight
    } else {
      asm volatile("s_waitcnt vmcnt(0)" ::: "memory");
    }
    __builtin_amdgcn_s_barrier();

    const ushort* lac = la + cur * 4096;
    const ushort* lbc = lb + cur * 2048;
    short8 af[4], bf[2];
#pragma unroll
    for (int mi = 0; mi < 4; ++mi) {
      const int rr = wr + mi * 16 + l15;
      af[mi] = *(const short8*)(lac + rr * 32 + (kq ^ ((rr & 6) << 2)));
    }
#pragma unroll
    for (int nj = 0; nj < 2; ++nj) {
      const int rr = wc + nj * 16 + l15;
      bf[nj] = *(const short8*)(lbc + rr * 32 + (kq ^ ((rr & 6) << 2)));
    }
#pragma unroll
    for (int mi = 0; mi < 4; ++mi)
#pragma unroll
      for (int nj = 0; nj < 2; ++nj)
        acc[mi][nj] = __builtin_amdgcn_mfma_f32_16x16x32_bf16(af[mi], bf[nj], acc[mi][nj], 0, 0, 0);

    asm volatile("s_waitcnt lgkmcnt(0)" ::: "memory");
    __builtin_amdgcn_s_barrier();   // reads done: next iter may overwrite
  }

#pragma unroll
  for (int nj = 0; nj < 2; ++nj) {
    const int col = bn + wc + nj * 16 + l15;
    const float bcol = bias[col];
#pragma unroll
    for (int mi = 0; mi < 4; ++mi) {
      const int rbase = bm + wr + mi * 16 + (lane >> 4) * 4;
#pragma unroll
      for (int b = 0; b < 4; ++b) {
        float v = acc[mi][nj][b] + bcol;
        O[(size_t)(rbase + b) * HID4 + col] = f2b(fmaxf(v, 0.f));
      }
    }
  }
}

// ------------------------------------------------------------------
// prep: mean-over-Q (+bf16 cast), 6 weight transposes, and an attn
// chunk — one launch, block roles.
// ------------------------------------------------------------------
__global__ __launch_bounds__(256) void prep_kernel(
    const float* __restrict__ qemb, const float* __restrict__ fpos,
    ushort* __restrict__ qe_b, ushort* __restrict__ fp_b,
    const float* __restrict__ ws1, ushort* __restrict__ wts1,
    const float* __restrict__ wp1, ushort* __restrict__ wtp1,
    const float* __restrict__ ws2, ushort* __restrict__ wts2,
    const float* __restrict__ wp2, ushort* __restrict__ wtp2,
    const float* __restrict__ ws3, ushort* __restrict__ wts3,
    const float* __restrict__ wp3, ushort* __restrict__ wtp3,
    const float* __restrict__ attn, float* __restrict__ pp,
    int n_mean_blocks, int n_trans_blocks, int total) {
  __shared__ PrepSM sm;
  const int tid = threadIdx.x;
  const int bid = blockIdx.x;

  if (bid < n_mean_blocks) {
    int idx = bid * 256 + tid;
    const int pairs = total >> 1;
    const float* src; ushort* dst; int i;
    if (idx < pairs) { src = qemb; dst = qe_b; i = idx; }
    else             { src = fpos; dst = fp_b; i = idx - pairs; }
    int nn = i / (HID / 2);
    int h = (i - nn * (HID / 2)) * 2;
    const float* p = src + (size_t)nn * (16 * HID) + h;
    float sx = 0.f, sy = 0.f;
#pragma unroll
    for (int q = 0; q < 16; ++q) {
      float2 v = *(const float2*)(p + q * HID);
      sx += v.x; sy += v.y;
    }
    ushort2 o;
    o.x = f2b(sx * 0.0625f);
    o.y = f2b(sy * 0.0625f);
    *(ushort2*)(dst + (size_t)nn * HID + h) = o;
    return;
  }

  if (bid < n_mean_blocks + n_trans_blocks) {
    int r = bid - n_mean_blocks;
    const float* in; ushort* out; int K;
    if (r < 100)       { in = ws1; out = wts1; K = HID; }
    else if (r < 200)  { in = wp1; out = wtp1; K = HID; r -= 100; }
    else if (r < 600)  { in = ws2; out = wts2; K = HID4; r -= 200; }
    else if (r < 1000) { in = wp2; out = wtp2; K = HID4; r -= 600; }
    else if (r < 1400) { in = ws3; out = wts3; K = HID4; r -= 1000; }
    else               { in = wp3; out = wtp3; K = HID4; r -= 1400; }
    const int bx = (r % 20) * 32;   // n base
    const int by = (r / 20) * 32;   // k base
    const int lx = tid & 31;
    const int ly = tid >> 5;
#pragma unroll
    for (int i = 0; i < 4; ++i)
      sm.t[ly + i * 8][lx] = in[(size_t)(by + ly + i * 8) * HID4 + bx + lx];
    __syncthreads();
#pragma unroll
    for (int i = 0; i < 4; ++i)
      out[(size_t)(bx + ly + i * 8) * K + by + lx] = f2b(sm.t[lx][ly + i * 8]);
    return;
  }

  attn_block(sm.a, attn, pp, bid - n_mean_blocks - n_trans_blocks);
}

// ------------------------------------------------------------------
// final: 640->1 and 640->4 dots per sample (one wave each) + combine
// ------------------------------------------------------------------
__global__ __launch_bounds__(256) void final_kernel(
    const ushort* __restrict__ hs, const ushort* __restrict__ hp,
    const float* __restrict__ ws4, const float* __restrict__ bs4,
    const float* __restrict__ wp4, const float* __restrict__ bp4,
    const float* __restrict__ pp, float* __restrict__ out, int N) {
  const int wid = threadIdx.x >> 6;
  const int lane = threadIdx.x & 63;
  const int n = blockIdx.x * 4 + wid;
  if (n >= N) return;
  const ushort* hsr = hs + (size_t)n * HID4;
  const ushort* hpr = hp + (size_t)n * HID4;
  float sc = 0.f, b0 = 0.f, b1 = 0.f, b2 = 0.f, b3 = 0.f;
  for (int j = lane; j < HID4; j += 64) {
    float h1 = b2f(hsr[j]);
    sc += h1 * ws4[j];
    float h2 = b2f(hpr[j]);
    b0 += h2 * wp4[j * 4 + 0];
    b1 += h2 * wp4[j * 4 + 1];
    b2 += h2 * wp4[j * 4 + 2];
    b3 += h2 * wp4[j * 4 + 3];
  }
  for (int off = 32; off > 0; off >>= 1) {
    sc += __shfl_down(sc, off);
    b0 += __shfl_down(b0, off);
    b1 += __shfl_down(b1, off);
    b2 += __shfl_down(b2, off);
    b3 += __shfl_down(b3, off);
  }
  if (lane == 0) {
    sc += bs4[0];
    b0 += bp4[0]; b1 += bp4[1]; b2 += bp4[2]; b3 += bp4[3];
    float so0 = fminf(fmaxf(b0, -2.f), 2.f);
    float so1 = fminf(fmaxf(b1, -2.f), 2.f);
    float po0 = fminf(fmaxf(b2, -2.f), 2.f);
    float po1 = fminf(fmaxf(b3, -2.f), 2.f);
    float px = pp[n * 4 + 0], py = pp[n * 4 + 1];
    float psx = pp[n * 4 + 2], psy = pp[n * 4 + 3];
    float wh0 = (psx + so0) * (1.f / 32.f);
    float wh1 = (psy + so1) * (1.f / 32.f);
    float xy0 = (px + po0) * (1.f / 32.f) - 0.5f * wh0;
    float xy1 = (py + po1) * (1.f / 32.f) - 0.5f * wh1;
    out[n * 4 + 0] = xy0;
    out[n * 4 + 1] = xy1;
    out[n * 4 + 2] = wh0;
    out[n * 4 + 3] = wh1;
    out[(size_t)4 * N + n] = sc;
  }
}

// ------------------------------------------------------------------
extern "C" void kernel_launch(void* const* d_in, const int* in_sizes, int n_in,
                              void* d_out, int out_size, void* d_ws, size_t ws_size,
                              hipStream_t stream) {
  const float* fpos = (const float*)d_in[0];
  const float* qemb = (const float*)d_in[1];
  const float* attn = (const float*)d_in[2];
  const float* ws1 = (const float*)d_in[3];
  const float* bs1 = (const float*)d_in[4];
  const float* ws2 = (const float*)d_in[5];
  const float* bs2 = (const float*)d_in[6];
  const float* ws3 = (const float*)d_in[7];
  const float* bs3 = (const float*)d_in[8];
  const float* ws4 = (const float*)d_in[9];
  const float* bs4 = (const float*)d_in[10];
  const float* wp1 = (const float*)d_in[11];
  const float* bp1 = (const float*)d_in[12];
  const float* wp2 = (const float*)d_in[13];
  const float* bp2 = (const float*)d_in[14];
  const float* wp3 = (const float*)d_in[15];
  const float* bp3 = (const float*)d_in[16];
  const float* wp4 = (const float*)d_in[17];
  const float* bp4 = (const float*)d_in[18];
  float* out = (float*)d_out;

  const int N = in_sizes[0] / (16 * HID);  // 4096

  char* ws = (char*)d_ws;
  const size_t SZ_QE = (size_t)N * HID * 2;
  const size_t SZ_W1 = (size_t)HID4 * HID * 2;
  const size_t SZ_W2 = (size_t)HID4 * HID4 * 2;
  const size_t SZ_H  = (size_t)N * HID4 * 2;
  size_t off = 0;
  ushort* qe_b = (ushort*)(ws + off); off += SZ_QE;
  ushort* fp_b = (ushort*)(ws + off); off += SZ_QE;
  ushort* wts1 = (ushort*)(ws + off); off += SZ_W1;
  ushort* wtp1 = (ushort*)(ws + off); off += SZ_W1;
  ushort* wts2 = (ushort*)(ws + off); off += SZ_W2;
  ushort* wtp2 = (ushort*)(ws + off); off += SZ_W2;
  ushort* wts3 = (ushort*)(ws + off); off += SZ_W2;
  ushort* wtp3 = (ushort*)(ws + off); off += SZ_W2;
  ushort* hsA  = (ushort*)(ws + off); off += SZ_H;
  ushort* hsB  = (ushort*)(ws + off); off += SZ_H;
  ushort* hpA  = (ushort*)(ws + off); off += SZ_H;
  ushort* hpB  = (ushort*)(ws + off); off += SZ_H;
  float*  pp   = (float*)(ws + off);  off += (size_t)N * 4 * 4;

  // attn sample distribution across the 4 overlappable launches
  const int a0 = (N * 25) / 64;          // prep (pure BW launch gets overflow)
  const int a1 = (N * 11) / 64;          // gemm1 (short: K=160)
  const int a2 = (N * 14) / 64;          // gemm2
  const int a3 = N - a0 - a1 - a2;       // gemm3

  const int total = N * HID;
  const int n_mean = (total + 255) / 256;      // threads = total (both tensors, float2 each)
  const int n_trans = 1800;
  prep_kernel<<<n_mean + n_trans + a0, 256, 0, stream>>>(
      qemb, fpos, qe_b, fp_b, ws1, wts1, wp1, wtp1, ws2, wts2, wp2, wtp2,
      ws3, wts3, wp3, wtp3, attn, pp, n_mean, n_trans, total);

  // GEMM grid per launch: 2 chains x (N/128) m x 10 n = 640 blocks
  const int n_gemm = 2 * (N / 128) * (HID4 / 64);

  gemm_attn<HID><<<n_gemm + a1, 256, 0, stream>>>(
      qe_b, fp_b, wts1, wtp1, bs1, bp1, hsA, hpA, attn, pp, a0, n_gemm);
  gemm_attn<HID4><<<n_gemm + a2, 256, 0, stream>>>(
      hsA, hpA, wts2, wtp2, bs2, bp2, hsB, hpB, attn, pp, a0 + a1, n_gemm);
  gemm_attn<HID4><<<n_gemm + a3, 256, 0, stream>>>(
      hsB, hpB, wts3, wtp3, bs3, bp3, hsA, hpA, attn, pp, a0 + a1 + a2, n_gemm);

  final_kernel<<<(N + 3) / 4, 256, 0, stream>>>(hsA, hpA, ws4, bs4, wp4, bp4, pp, out, N);
}

// Round 4
// 126.420 us; speedup vs baseline: 1.0424x; 1.0424x over previous
//
#include <hip/hip_runtime.h>
#include <hip/hip_bf16.h>
#include <stdint.h>

#define HID 160
#define HID4 640
#define FDIM 32
#define NPIX 1024

// Gaussian blur taps: e = exp(-0.5); k = [e,1,e]/(1+2e)
#define GK0 0.27406862f
#define GK1 0.45186276f

typedef __attribute__((ext_vector_type(8))) short short8;
typedef __attribute__((ext_vector_type(4))) float f32x4;

__device__ __forceinline__ ushort f2b(float f) {
  union { float f; uint32_t u; } v; v.f = f;
  uint32_t u = v.u;
  u += 0x7fffu + ((u >> 16) & 1u);   // RNE
  return (ushort)(u >> 16);
}
__device__ __forceinline__ float b2f(ushort s) {
  union { uint32_t u; float f; } v; v.u = ((uint32_t)s) << 16;
  return v.f;
}

// async global->LDS, 16B per lane; LDS dest = wave-uniform base + lane*16
__device__ __forceinline__ void gload16(const ushort* g, ushort* l) {
  __builtin_amdgcn_global_load_lds(
      (const __attribute__((address_space(1))) void*)g,
      (__attribute__((address_space(3))) void*)l, 16, 0, 0);
}

// ------------------------------------------------------------------
// attn per-sample scratch (shared by kernels via unions)
// ------------------------------------------------------------------
struct AttnSM {
  float am[FDIM][FDIM + 1];
  float tmp[FDIM][FDIM + 1];
  float bl[FDIM][FDIM + 1];
  float rowsum[FDIM], colsum[FDIM];
  float redv[4];
  int redi[4];
};

union GemmSM {
  struct {
    ushort la[128 * 160];   // 40 KB, linear (global_load_lds requirement)
    ushort lb[128 * 160];   // 40 KB
  } g;
  AttnSM a;
};

union PrepSM {
  float t[32][33];
  AttnSM a;
};

__device__ void attn_block(AttnSM& sm, const float* __restrict__ attn,
                           float* __restrict__ pp, int n) {
  const int tid = threadIdx.x;
  const float* base = attn + (size_t)n * (16 * NPIX);
  float4 a = make_float4(0.f, 0.f, 0.f, 0.f);
#pragma unroll
  for (int q = 0; q < 16; ++q) {
    float4 v = *(const float4*)(base + q * NPIX + tid * 4);
    a.x += v.x; a.y += v.y; a.z += v.z; a.w += v.w;
  }
  {
    const int f0 = tid * 4;
    const int r = f0 >> 5, c = f0 & 31;
    sm.am[r][c + 0] = a.x * 0.0625f;
    sm.am[r][c + 1] = a.y * 0.0625f;
    sm.am[r][c + 2] = a.z * 0.0625f;
    sm.am[r][c + 3] = a.w * 0.0625f;
  }
  __syncthreads();
  for (int f = tid; f < NPIX; f += 256) {
    int r = f >> 5, c = f & 31;
    int rm = (r == 0) ? 1 : r - 1;
    int rp = (r == 31) ? 30 : r + 1;
    sm.tmp[r][c] = GK0 * sm.am[rm][c] + GK1 * sm.am[r][c] + GK0 * sm.am[rp][c];
  }
  __syncthreads();
  for (int f = tid; f < NPIX; f += 256) {
    int r = f >> 5, c = f & 31;
    int cm = (c == 0) ? 1 : c - 1;
    int cp = (c == 31) ? 30 : c + 1;
    sm.bl[r][c] = GK0 * sm.tmp[r][cm] + GK1 * sm.tmp[r][c] + GK0 * sm.tmp[r][cp];
  }
  __syncthreads();
  // argmax of blurred map (normalization is affine+positive => argmax-invariant)
  float bv = -1e30f; int bi = 0;
  for (int f = tid; f < NPIX; f += 256) {
    float v = sm.bl[f >> 5][f & 31];
    if (v > bv || (v == bv && f < bi)) { bv = v; bi = f; }
  }
  for (int off = 32; off > 0; off >>= 1) {
    float ov = __shfl_down(bv, off);
    int oi = __shfl_down(bi, off);
    if (ov > bv || (ov == bv && oi < bi)) { bv = ov; bi = oi; }
  }
  if ((tid & 63) == 0) { sm.redv[tid >> 6] = bv; sm.redi[tid >> 6] = bi; }
  for (int f = tid; f < NPIX; f += 256) {
    int r = f >> 5, c = f & 31;
    float s = 1.f / (1.f + expf(-sm.am[r][c]));
    sm.tmp[r][c] = fminf(fmaxf(s, 1e-4f), 0.9999f);
  }
  __syncthreads();
  if (tid < 32) {
    float s = 0.f;
    for (int c = 0; c < 32; ++c) s += sm.tmp[tid][c];
    sm.rowsum[tid] = s;
  } else if (tid < 64) {
    int c = tid - 32;
    float s = 0.f;
    for (int r = 0; r < 32; ++r) s += sm.tmp[r][c];
    sm.colsum[c] = s;
  }
  __syncthreads();
  if (tid == 0) {
    float bestv = sm.redv[0]; int besti = sm.redi[0];
    for (int w = 1; w < 4; ++w)
      if (sm.redv[w] > bestv || (sm.redv[w] == bestv && sm.redi[w] < besti)) {
        bestv = sm.redv[w]; besti = sm.redi[w];
      }
    int px = besti & 31, py = besti >> 5;
    int c0 = max(0, px - 3), c1 = min(32, px + 3);
    float sx = 0.f;
    for (int c = c0; c < c1; ++c) sx += sm.colsum[c];
    float psx = (sx / (32.f * (float)(c1 - c0))) * 32.f;
    int r0 = max(0, py - 3), r1 = min(32, py + 3);
    float sy = 0.f;
    for (int r = r0; r < r1; ++r) sy += sm.rowsum[r];
    float psy = (sy / (32.f * (float)(r1 - r0))) * 32.f;
    pp[n * 4 + 0] = (float)px;
    pp[n * 4 + 1] = (float)py;
    pp[n * 4 + 2] = psx;
    pp[n * 4 + 3] = psy;
  }
}

// ------------------------------------------------------------------
// Fused: 128x128-tile MFMA GEMM with BK=160 (only K/160 vmcnt drains
// on the critical path; 1 for gemm1, 4 for gemm2/3), simple
// __syncthreads loop; + a small attn chunk in the same grid.
// ------------------------------------------------------------------
template <int K>
__global__ __launch_bounds__(256, 2) void gemm_attn(
    const ushort* __restrict__ A0, const ushort* __restrict__ A1,
    const ushort* __restrict__ W0, const ushort* __restrict__ W1,
    const float* __restrict__ B0, const float* __restrict__ B1,
    ushort* __restrict__ O0, ushort* __restrict__ O1,
    const float* __restrict__ attn, float* __restrict__ pp,
    int attn_base, int n_gemm) {
  __shared__ GemmSM sm;
  const int tid = threadIdx.x;

  if ((int)blockIdx.x >= n_gemm) {
    attn_block(sm.a, attn, pp, attn_base + (int)blockIdx.x - n_gemm);
    return;
  }

  const int bid = blockIdx.x;
  const int half = n_gemm >> 1;
  const int chain = bid >= half;
  const int r = chain ? bid - half : bid;
  const int bn = (r % 5) * 128;
  const int bm = (r / 5) * 128;
  const ushort* A = chain ? A1 : A0;
  const ushort* W = chain ? W1 : W0;
  const float* bias = chain ? B1 : B0;
  ushort* O = chain ? O1 : O0;

  const int lane = tid & 63;
  const int wid = tid >> 6;
  const int wr = (wid >> 1) * 64;
  const int wc = (wid & 1) * 64;
  const int l15 = lane & 15;
  const int kq = (lane >> 4) * 8;

  ushort* la = sm.g.la;
  ushort* lb = sm.g.lb;

  // Precompute per-lane global element offsets for the 10 A-chunks and
  // 10 B-chunks this wave stages per K-step (each chunk = 1 KB = 512 elems,
  // LDS dest wave-uniform, global src per-lane).
  uint offA[10], offB[10];
#pragma unroll
  for (int i = 0; i < 10; ++i) {
    const uint e = (uint)(wid * 10 + i) * 512 + lane * 8;
    const uint row = e / 160;
    const uint col = e - row * 160;
    offA[i] = (uint)(bm + row) * K + col;
    offB[i] = (uint)(bn + row) * K + col;
  }

  constexpr int NT = K / 160;
  f32x4 acc[4][4] = {};
  for (int t = 0; t < NT; ++t) {
    const int k0 = t * 160;
#pragma unroll
    for (int i = 0; i < 10; ++i) {
      const int ldso = (wid * 10 + i) * 512;
      gload16(A + offA[i] + k0, la + ldso);
      gload16(W + offB[i] + k0, lb + ldso);
    }
    __syncthreads();   // drain vmcnt: tiles resident
#pragma unroll
    for (int ks = 0; ks < 5; ++ks) {
      short8 af[4], bf[4];
#pragma unroll
      for (int i = 0; i < 4; ++i) {
        af[i] = *(const short8*)(la + (wr + i * 16 + l15) * 160 + ks * 32 + kq);
        bf[i] = *(const short8*)(lb + (wc + i * 16 + l15) * 160 + ks * 32 + kq);
      }
#pragma unroll
      for (int mi = 0; mi < 4; ++mi)
#pragma unroll
        for (int nj = 0; nj < 4; ++nj)
          acc[mi][nj] = __builtin_amdgcn_mfma_f32_16x16x32_bf16(af[mi], bf[nj], acc[mi][nj], 0, 0, 0);
    }
    if (t + 1 < NT) __syncthreads();   // reads done before overwrite
  }

#pragma unroll
  for (int nj = 0; nj < 4; ++nj) {
    const int col = bn + wc + nj * 16 + l15;
    const float bcol = bias[col];
#pragma unroll
    for (int mi = 0; mi < 4; ++mi) {
      const int rbase = bm + wr + mi * 16 + (lane >> 4) * 4;
#pragma unroll
      for (int b = 0; b < 4; ++b) {
        float v = acc[mi][nj][b] + bcol;
        O[(size_t)(rbase + b) * HID4 + col] = f2b(fmaxf(v, 0.f));
      }
    }
  }
}

// ------------------------------------------------------------------
// prep: mean-over-Q (+bf16 cast), 6 weight transposes, and the bulk
// of the attn samples — one launch, block roles, high occupancy.
// ------------------------------------------------------------------
__global__ __launch_bounds__(256, 4) void prep_kernel(
    const float* __restrict__ qemb, const float* __restrict__ fpos,
    ushort* __restrict__ qe_b, ushort* __restrict__ fp_b,
    const float* __restrict__ ws1, ushort* __restrict__ wts1,
    const float* __restrict__ wp1, ushort* __restrict__ wtp1,
    const float* __restrict__ ws2, ushort* __restrict__ wts2,
    const float* __restrict__ wp2, ushort* __restrict__ wtp2,
    const float* __restrict__ ws3, ushort* __restrict__ wts3,
    const float* __restrict__ wp3, ushort* __restrict__ wtp3,
    const float* __restrict__ attn, float* __restrict__ pp,
    int n_mean_blocks, int n_trans_blocks, int total) {
  __shared__ PrepSM sm;
  const int tid = threadIdx.x;
  const int bid = blockIdx.x;

  if (bid < n_mean_blocks) {
    int idx = bid * 256 + tid;
    const int pairs = total >> 1;
    const float* src; ushort* dst; int i;
    if (idx < pairs) { src = qemb; dst = qe_b; i = idx; }
    else             { src = fpos; dst = fp_b; i = idx - pairs; }
    int nn = i / (HID / 2);
    int h = (i - nn * (HID / 2)) * 2;
    const float* p = src + (size_t)nn * (16 * HID) + h;
    float sx = 0.f, sy = 0.f;
#pragma unroll
    for (int q = 0; q < 16; ++q) {
      float2 v = *(const float2*)(p + q * HID);
      sx += v.x; sy += v.y;
    }
    ushort2 o;
    o.x = f2b(sx * 0.0625f);
    o.y = f2b(sy * 0.0625f);
    *(ushort2*)(dst + (size_t)nn * HID + h) = o;
    return;
  }

  if (bid < n_mean_blocks + n_trans_blocks) {
    int r = bid - n_mean_blocks;
    const float* in; ushort* out; int K;
    if (r < 100)       { in = ws1; out = wts1; K = HID; }
    else if (r < 200)  { in = wp1; out = wtp1; K = HID; r -= 100; }
    else if (r < 600)  { in = ws2; out = wts2; K = HID4; r -= 200; }
    else if (r < 1000) { in = wp2; out = wtp2; K = HID4; r -= 600; }
    else if (r < 1400) { in = ws3; out = wts3; K = HID4; r -= 1000; }
    else               { in = wp3; out = wtp3; K = HID4; r -= 1400; }
    const int bx = (r % 20) * 32;   // n base
    const int by = (r / 20) * 32;   // k base
    const int lx = tid & 31;
    const int ly = tid >> 5;
#pragma unroll
    for (int i = 0; i < 4; ++i)
      sm.t[ly + i * 8][lx] = in[(size_t)(by + ly + i * 8) * HID4 + bx + lx];
    __syncthreads();
#pragma unroll
    for (int i = 0; i < 4; ++i)
      out[(size_t)(bx + ly + i * 8) * K + by + lx] = f2b(sm.t[lx][ly + i * 8]);
    return;
  }

  attn_block(sm.a, attn, pp, bid - n_mean_blocks - n_trans_blocks);
}

// ------------------------------------------------------------------
// final: 640->1 and 640->4 dots per sample (one wave each) + combine
// ------------------------------------------------------------------
__global__ __launch_bounds__(256) void final_kernel(
    const ushort* __restrict__ hs, const ushort* __restrict__ hp,
    const float* __restrict__ ws4, const float* __restrict__ bs4,
    const float* __restrict__ wp4, const float* __restrict__ bp4,
    const float* __restrict__ pp, float* __restrict__ out, int N) {
  const int wid = threadIdx.x >> 6;
  const int lane = threadIdx.x & 63;
  const int n = blockIdx.x * 4 + wid;
  if (n >= N) return;
  const ushort* hsr = hs + (size_t)n * HID4;
  const ushort* hpr = hp + (size_t)n * HID4;
  float sc = 0.f, b0 = 0.f, b1 = 0.f, b2 = 0.f, b3 = 0.f;
  for (int j = lane; j < HID4; j += 64) {
    float h1 = b2f(hsr[j]);
    sc += h1 * ws4[j];
    float h2 = b2f(hpr[j]);
    b0 += h2 * wp4[j * 4 + 0];
    b1 += h2 * wp4[j * 4 + 1];
    b2 += h2 * wp4[j * 4 + 2];
    b3 += h2 * wp4[j * 4 + 3];
  }
  for (int off = 32; off > 0; off >>= 1) {
    sc += __shfl_down(sc, off);
    b0 += __shfl_down(b0, off);
    b1 += __shfl_down(b1, off);
    b2 += __shfl_down(b2, off);
    b3 += __shfl_down(b3, off);
  }
  if (lane == 0) {
    sc += bs4[0];
    b0 += bp4[0]; b1 += bp4[1]; b2 += bp4[2]; b3 += bp4[3];
    float so0 = fminf(fmaxf(b0, -2.f), 2.f);
    float so1 = fminf(fmaxf(b1, -2.f), 2.f);
    float po0 = fminf(fmaxf(b2, -2.f), 2.f);
    float po1 = fminf(fmaxf(b3, -2.f), 2.f);
    float px = pp[n * 4 + 0], py = pp[n * 4 + 1];
    float psx = pp[n * 4 + 2], psy = pp[n * 4 + 3];
    float wh0 = (psx + so0) * (1.f / 32.f);
    float wh1 = (psy + so1) * (1.f / 32.f);
    float xy0 = (px + po0) * (1.f / 32.f) - 0.5f * wh0;
    float xy1 = (py + po1) * (1.f / 32.f) - 0.5f * wh1;
    out[n * 4 + 0] = xy0;
    out[n * 4 + 1] = xy1;
    out[n * 4 + 2] = wh0;
    out[n * 4 + 3] = wh1;
    out[(size_t)4 * N + n] = sc;
  }
}

// ------------------------------------------------------------------
extern "C" void kernel_launch(void* const* d_in, const int* in_sizes, int n_in,
                              void* d_out, int out_size, void* d_ws, size_t ws_size,
                              hipStream_t stream) {
  const float* fpos = (const float*)d_in[0];
  const float* qemb = (const float*)d_in[1];
  const float* attn = (const float*)d_in[2];
  const float* ws1 = (const float*)d_in[3];
  const float* bs1 = (const float*)d_in[4];
  const float* ws2 = (const float*)d_in[5];
  const float* bs2 = (const float*)d_in[6];
  const float* ws3 = (const float*)d_in[7];
  const float* bs3 = (const float*)d_in[8];
  const float* ws4 = (const float*)d_in[9];
  const float* bs4 = (const float*)d_in[10];
  const float* wp1 = (const float*)d_in[11];
  const float* bp1 = (const float*)d_in[12];
  const float* wp2 = (const float*)d_in[13];
  const float* bp2 = (const float*)d_in[14];
  const float* wp3 = (const float*)d_in[15];
  const float* bp3 = (const float*)d_in[16];
  const float* wp4 = (const float*)d_in[17];
  const float* bp4 = (const float*)d_in[18];
  float* out = (float*)d_out;

  const int N = in_sizes[0] / (16 * HID);  // 4096

  char* ws = (char*)d_ws;
  const size_t SZ_QE = (size_t)N * HID * 2;
  const size_t SZ_W1 = (size_t)HID4 * HID * 2;
  const size_t SZ_W2 = (size_t)HID4 * HID4 * 2;
  const size_t SZ_H  = (size_t)N * HID4 * 2;
  size_t off = 0;
  ushort* qe_b = (ushort*)(ws + off); off += SZ_QE;
  ushort* fp_b = (ushort*)(ws + off); off += SZ_QE;
  ushort* wts1 = (ushort*)(ws + off); off += SZ_W1;
  ushort* wtp1 = (ushort*)(ws + off); off += SZ_W1;
  ushort* wts2 = (ushort*)(ws + off); off += SZ_W2;
  ushort* wtp2 = (ushort*)(ws + off); off += SZ_W2;
  ushort* wts3 = (ushort*)(ws + off); off += SZ_W2;
  ushort* wtp3 = (ushort*)(ws + off); off += SZ_W2;
  ushort* hsA  = (ushort*)(ws + off); off += SZ_H;
  ushort* hsB  = (ushort*)(ws + off); off += SZ_H;
  ushort* hpA  = (ushort*)(ws + off); off += SZ_H;
  ushort* hpB  = (ushort*)(ws + off); off += SZ_H;
  float*  pp   = (float*)(ws + off);  off += (size_t)N * 4 * 4;

  // attn distribution: bulk in prep (high occupancy), small chunks in
  // gemm launches sized to their (now short) critical paths.
  const int a1 = 350;
  const int a2 = 600;
  const int a3 = 600;
  const int a0 = N - a1 - a2 - a3;   // 2546

  const int total = N * HID;
  const int n_mean = (total + 255) / 256;
  const int n_trans = 1800;
  prep_kernel<<<n_mean + n_trans + a0, 256, 0, stream>>>(
      qemb, fpos, qe_b, fp_b, ws1, wts1, wp1, wtp1, ws2, wts2, wp2, wtp2,
      ws3, wts3, wp3, wtp3, attn, pp, n_mean, n_trans, total);

  // GEMM grid per launch: 2 chains x (N/128) m x 5 n = 320 blocks
  const int n_gemm = 2 * (N / 128) * (HID4 / 128);

  gemm_attn<HID><<<n_gemm + a1, 256, 0, stream>>>(
      qe_b, fp_b, wts1, wtp1, bs1, bp1, hsA, hpA, attn, pp, a0, n_gemm);
  gemm_attn<HID4><<<n_gemm + a2, 256, 0, stream>>>(
      hsA, hpA, wts2, wtp2, bs2, bp2, hsB, hpB, attn, pp, a0 + a1, n_gemm);
  gemm_attn<HID4><<<n_gemm + a3, 256, 0, stream>>>(
      hsB, hpB, wts3, wtp3, bs3, bp3, hsA, hpA, attn, pp, a0 + a1 + a2, n_gemm);

  final_kernel<<<(N + 3) / 4, 256, 0, stream>>>(hsA, hpA, ws4, bs4, wp4, bp4, pp, out, N);
}